// Round 5
// baseline (331.852 us; speedup 1.0000x reference)
//
#include <hip/hip_runtime.h>
#include <math.h>

#define BB 256
#define LL 500
#define EE 300
#define NROWS (BB * LL)      // 128000
#define NJ 18                // 3 (aw3) + 1 (cw3) + 5 (aw5) + 1 (cw5) + 7 (aw7) + 1 (cw7)
#define NC 75                // float4 chunks per row
#define TOUT 56              // outputs per block
#define NTILE 9              // ceil(500/56)
#define DROWS 64             // dot rows per block = TOUT + 6 halo (+2 spare)

// ---------------------------------------------------------------------------
// Fully fused, weights-in-LDS, x software-pipelined.
// Block = 256 thr = 4 waves; wave -> 4 groups x 16 lanes; group -> 4 rows.
// 64 dot-rows/block; epilogue combines taps + sigmoid + tanh. No workspace.
// R4 was latency-bound (VALUBusy 21%, 80% stall): 90 weight loads/wave from
// global serialized. Now weights come from LDS (conflict-free b128 reads)
// and the 20 x-loads/lane are double-buffered in registers.
// ---------------------------------------------------------------------------
__global__ __launch_bounds__(256, 4) void fused_kernel(
    const float* __restrict__ x,
    const float* __restrict__ aw3, const float* __restrict__ ab3,
    const float* __restrict__ cw3, const float* __restrict__ cb3,
    const float* __restrict__ aw5, const float* __restrict__ ab5,
    const float* __restrict__ cw5, const float* __restrict__ cb5,
    const float* __restrict__ aw7, const float* __restrict__ ab7,
    const float* __restrict__ cw7, const float* __restrict__ cb7,
    float* __restrict__ out)
{
    __shared__ float4 wlds[NJ][NC];          // 18*75*16 = 21.6 KB
    __shared__ float dlds[DROWS][NJ + 1];    // stride 19, conflict-free (4.9 KB)
    __shared__ const float4* wbase[NJ];

    const int tid = threadIdx.x;

    if (tid == 0) {
        wbase[0]  = (const float4*)(aw3);
        wbase[1]  = (const float4*)(aw3 + 300);
        wbase[2]  = (const float4*)(aw3 + 600);
        wbase[3]  = (const float4*)(cw3);
        wbase[4]  = (const float4*)(aw5);
        wbase[5]  = (const float4*)(aw5 + 300);
        wbase[6]  = (const float4*)(aw5 + 600);
        wbase[7]  = (const float4*)(aw5 + 900);
        wbase[8]  = (const float4*)(aw5 + 1200);
        wbase[9]  = (const float4*)(cw5);
        wbase[10] = (const float4*)(aw7);
        wbase[11] = (const float4*)(aw7 + 300);
        wbase[12] = (const float4*)(aw7 + 600);
        wbase[13] = (const float4*)(aw7 + 900);
        wbase[14] = (const float4*)(aw7 + 1200);
        wbase[15] = (const float4*)(aw7 + 1500);
        wbase[16] = (const float4*)(aw7 + 1800);
        wbase[17] = (const float4*)(cw7);
    }

    const int b    = blockIdx.x / NTILE;
    const int t    = blockIdx.x % NTILE;
    const int l0   = t * TOUT - 3;           // global l of local dot-row 0
    const int wave = tid >> 6;               // 0..3
    const int lane = tid & 63;
    const int g    = lane >> 4;              // 0..3
    const int j    = lane & 15;              // 0..15
    const int lr   = wave * 16 + g * 4;      // local dot-row base (0..60)

    // clamped x row pointers + validity (invalid rows -> zero dots = zero pad)
    bool valid[4];
    const float4* xr[4];
#pragma unroll
    for (int rr = 0; rr < 4; ++rr) {
        const int l = l0 + lr + rr;
        valid[rr] = (l >= 0) && (l < LL);
        const int lc = l < 0 ? 0 : (l >= LL ? LL - 1 : l);
        xr[rr] = (const float4*)(x + ((size_t)b * LL + lc) * EE);
    }

    // kick off first x chunk before weight staging (independent of LDS)
    float4 xc[4];
#pragma unroll
    for (int rr = 0; rr < 4; ++rr) xc[rr] = xr[rr][j];

    __syncthreads();   // wbase visible
    // cooperative weight staging: 1350 float4 across 256 threads
    for (int i = tid; i < NJ * NC; i += 256) {
        const int d = i / NC;
        const int c = i - d * NC;
        wlds[d][c] = wbase[d][c];
    }
    __syncthreads();   // wlds visible

    float acc[NJ][4];
#pragma unroll
    for (int d = 0; d < NJ; ++d)
#pragma unroll
        for (int rr = 0; rr < 4; ++rr) acc[d][rr] = 0.0f;

#define COMPUTE(c)                                                                  \
    {                                                                               \
        _Pragma("unroll")                                                           \
        for (int d = 0; d < NJ; ++d) {                                              \
            const float4 w = wlds[d][(c)];                                          \
            acc[d][0] = fmaf(xc[0].w, w.w, fmaf(xc[0].z, w.z, fmaf(xc[0].y, w.y, fmaf(xc[0].x, w.x, acc[d][0])))); \
            acc[d][1] = fmaf(xc[1].w, w.w, fmaf(xc[1].z, w.z, fmaf(xc[1].y, w.y, fmaf(xc[1].x, w.x, acc[d][1])))); \
            acc[d][2] = fmaf(xc[2].w, w.w, fmaf(xc[2].z, w.z, fmaf(xc[2].y, w.y, fmaf(xc[2].x, w.x, acc[d][2])))); \
            acc[d][3] = fmaf(xc[3].w, w.w, fmaf(xc[3].z, w.z, fmaf(xc[3].y, w.y, fmaf(xc[3].x, w.x, acc[d][3])))); \
        }                                                                           \
    }

    // software-pipelined chunk loop: chunks j, j+16, j+32, j+48, j+64(pred)
    float4 xn[4];
#pragma unroll
    for (int k = 0; k < 4; ++k) {
        const int cn = (k == 3) ? ((j < 11) ? (j + 64) : 74) : (j + 16 * (k + 1));
#pragma unroll
        for (int rr = 0; rr < 4; ++rr) xn[rr] = xr[rr][cn];   // prefetch next
        COMPUTE(j + 16 * k)                                   // compute current
#pragma unroll
        for (int rr = 0; rr < 4; ++rr) xc[rr] = xn[rr];
    }
    if (j < 11) {
        COMPUTE(j + 64)
    }
#undef COMPUTE

    // butterfly reduce each (d, rr) across the 16-lane group
#pragma unroll
    for (int d = 0; d < NJ; ++d)
#pragma unroll
        for (int rr = 0; rr < 4; ++rr) {
            float v = acc[d][rr];
            v += __shfl_xor(v, 1, 16);
            v += __shfl_xor(v, 2, 16);
            v += __shfl_xor(v, 4, 16);
            v += __shfl_xor(v, 8, 16);
            acc[d][rr] = v;
        }

    // lane j == rr stores row lr+rr into LDS (zeroed if out-of-range)
#pragma unroll
    for (int rr = 0; rr < 4; ++rr) {
        if (j == rr) {
            const float vf = valid[rr] ? 1.0f : 0.0f;
#pragma unroll
            for (int d = 0; d < NJ; ++d) dlds[lr + rr][d] = acc[d][rr] * vf;
        }
    }

    __syncthreads();

    // epilogue: thread tid < TOUT handles output l = t*TOUT + tid
    if (tid < TOUT) {
        const int lo = t * TOUT + tid;
        if (lo < LL) {
            const int c = tid + 3;   // local dot-row of the center

            float pre3 = 0.0f, pre5 = 0.0f, pre7 = 0.0f;
#pragma unroll
            for (int tp = 0; tp < 3; ++tp) pre3 += dlds[c + tp - 1][tp];
#pragma unroll
            for (int tp = 0; tp < 5; ++tp) pre5 += dlds[c + tp - 2][4 + tp];
#pragma unroll
            for (int tp = 0; tp < 7; ++tp) pre7 += dlds[c + tp - 3][10 + tp];

            const float c3v = dlds[c][3];
            const float c5v = dlds[c][9];
            const float c7v = dlds[c][17];

            const float s3 = 1.0f / (1.0f + expf(-(pre3 + ab3[0])));
            const float s5 = 1.0f / (1.0f + expf(-(pre5 + ab5[0])));
            const float s7 = 1.0f / (1.0f + expf(-(pre7 + ab7[0])));

            const int r = b * LL + lo;
            out[r]             = tanhf(s3 * c3v + cb3[0]);
            out[NROWS + r]     = tanhf(s5 * c5v + cb5[0]);
            out[2 * NROWS + r] = tanhf(s7 * c7v + cb7[0]);
        }
    }
}

extern "C" void kernel_launch(void* const* d_in, const int* in_sizes, int n_in,
                              void* d_out, int out_size, void* d_ws, size_t ws_size,
                              hipStream_t stream) {
    const float* x   = (const float*)d_in[0];
    const float* aw3 = (const float*)d_in[1];
    const float* ab3 = (const float*)d_in[2];
    const float* cw3 = (const float*)d_in[3];
    const float* cb3 = (const float*)d_in[4];
    const float* aw5 = (const float*)d_in[5];
    const float* ab5 = (const float*)d_in[6];
    const float* cw5 = (const float*)d_in[7];
    const float* cb5 = (const float*)d_in[8];
    const float* aw7 = (const float*)d_in[9];
    const float* ab7 = (const float*)d_in[10];
    const float* cw7 = (const float*)d_in[11];
    const float* cb7 = (const float*)d_in[12];

    float* out = (float*)d_out;  // [out3 | out5 | out7]

    // 256 batches x 9 l-tiles, one dispatch, no workspace
    fused_kernel<<<BB * NTILE, 256, 0, stream>>>(
        x, aw3, ab3, cw3, cb3, aw5, ab5, cw5, cb5, aw7, ab7, cw7, cb7, out);
}

// Round 6
// 261.738 us; speedup vs baseline: 1.2679x; 1.2679x over previous
//
#include <hip/hip_runtime.h>
#include <math.h>

#define BB 256
#define LL 500
#define EE 300
#define NROWS (BB * LL)      // 128000
#define NJ 18                // 3 (aw3) + 1 (cw3) + 5 (aw5) + 1 (cw5) + 7 (aw7) + 1 (cw7)
#define NC 75                // float4 chunks per row
#define TOUT 56              // outputs per block
#define NTILE 9              // ceil(500/56)
#define DROWS 64             // dot rows per block = TOUT + 6 halo (+2 spare)

// ---------------------------------------------------------------------------
// Fully fused, weights-in-LDS, x software-pipelined. NO occupancy bound:
// R5's __launch_bounds__(256,4) capped VGPRs at 64 -> 219MB scratch spill.
// Block = 256 thr = 4 waves; wave -> 4 groups x 16 lanes; group -> 4 rows.
// LDS weight image rows (order == dot order): 0-2 aw3, 3 cw3, 4-8 aw5,
// 9 cw5, 10-16 aw7, 17 cw7 -- each source array is contiguous, so staging
// is 6 flat vector copies (no division, fully coalesced).
// ---------------------------------------------------------------------------
__global__ __launch_bounds__(256) void fused_kernel(
    const float* __restrict__ x,
    const float* __restrict__ aw3, const float* __restrict__ ab3,
    const float* __restrict__ cw3, const float* __restrict__ cb3,
    const float* __restrict__ aw5, const float* __restrict__ ab5,
    const float* __restrict__ cw5, const float* __restrict__ cb5,
    const float* __restrict__ aw7, const float* __restrict__ ab7,
    const float* __restrict__ cw7, const float* __restrict__ cb7,
    float* __restrict__ out)
{
    __shared__ float4 wlds[NJ * NC];         // 1350 float4 = 21.6 KB
    __shared__ float dlds[DROWS][NJ + 1];    // stride 19, conflict-free (4.9 KB)

    const int tid = threadIdx.x;

    // ---- cooperative weight staging: 6 contiguous segments ----
    {
        const float4* s3a = (const float4*)aw3;   // 225
        const float4* s3c = (const float4*)cw3;   // 75
        const float4* s5a = (const float4*)aw5;   // 375
        const float4* s5c = (const float4*)cw5;   // 75
        const float4* s7a = (const float4*)aw7;   // 525
        const float4* s7c = (const float4*)cw7;   // 75
        for (int i = tid; i < 225; i += 256) wlds[i]        = s3a[i];
        for (int i = tid; i < 75;  i += 256) wlds[225 + i]  = s3c[i];
        for (int i = tid; i < 375; i += 256) wlds[300 + i]  = s5a[i];
        for (int i = tid; i < 75;  i += 256) wlds[675 + i]  = s5c[i];
        for (int i = tid; i < 525; i += 256) wlds[750 + i]  = s7a[i];
        for (int i = tid; i < 75;  i += 256) wlds[1275 + i] = s7c[i];
    }

    const int b    = blockIdx.x / NTILE;
    const int t    = blockIdx.x % NTILE;
    const int l0   = t * TOUT - 3;           // global l of local dot-row 0
    const int wave = tid >> 6;               // 0..3
    const int lane = tid & 63;
    const int g    = lane >> 4;              // 0..3
    const int j    = lane & 15;              // 0..15
    const int lr   = wave * 16 + g * 4;      // local dot-row base (0..60)

    // clamped x row pointers + validity (invalid rows -> zero dots = zero pad)
    bool valid[4];
    const float4* xr[4];
#pragma unroll
    for (int rr = 0; rr < 4; ++rr) {
        const int l = l0 + lr + rr;
        valid[rr] = (l >= 0) && (l < LL);
        const int lc = l < 0 ? 0 : (l >= LL ? LL - 1 : l);
        xr[rr] = (const float4*)(x + ((size_t)b * LL + lc) * EE);
    }

    // first x chunk loads overlap with weight staging (no LDS dependency)
    float4 xc[4];
#pragma unroll
    for (int rr = 0; rr < 4; ++rr) xc[rr] = xr[rr][j];

    __syncthreads();   // wlds visible

    float acc[NJ][4];
#pragma unroll
    for (int d = 0; d < NJ; ++d)
#pragma unroll
        for (int rr = 0; rr < 4; ++rr) acc[d][rr] = 0.0f;

#define COMPUTE(c)                                                                  \
    {                                                                               \
        _Pragma("unroll")                                                           \
        for (int d = 0; d < NJ; ++d) {                                              \
            const float4 w = wlds[d * NC + (c)];                                    \
            acc[d][0] = fmaf(xc[0].w, w.w, fmaf(xc[0].z, w.z, fmaf(xc[0].y, w.y, fmaf(xc[0].x, w.x, acc[d][0])))); \
            acc[d][1] = fmaf(xc[1].w, w.w, fmaf(xc[1].z, w.z, fmaf(xc[1].y, w.y, fmaf(xc[1].x, w.x, acc[d][1])))); \
            acc[d][2] = fmaf(xc[2].w, w.w, fmaf(xc[2].z, w.z, fmaf(xc[2].y, w.y, fmaf(xc[2].x, w.x, acc[d][2])))); \
            acc[d][3] = fmaf(xc[3].w, w.w, fmaf(xc[3].z, w.z, fmaf(xc[3].y, w.y, fmaf(xc[3].x, w.x, acc[d][3])))); \
        }                                                                           \
    }

    // software-pipelined chunk loop: chunks j, j+16, j+32, j+48, j+64(pred)
#pragma unroll
    for (int k = 0; k < 4; ++k) {
        const int cn = (k == 3) ? ((j < 11) ? (j + 64) : 74) : (j + 16 * (k + 1));
        float4 xn[4];
#pragma unroll
        for (int rr = 0; rr < 4; ++rr) xn[rr] = xr[rr][cn];   // prefetch next
        COMPUTE(j + 16 * k)                                   // compute current
#pragma unroll
        for (int rr = 0; rr < 4; ++rr) xc[rr] = xn[rr];
    }
    if (j < 11) {
        COMPUTE(j + 64)
    }
#undef COMPUTE

    // butterfly reduce each (d, rr) across the 16-lane group
#pragma unroll
    for (int d = 0; d < NJ; ++d)
#pragma unroll
        for (int rr = 0; rr < 4; ++rr) {
            float v = acc[d][rr];
            v += __shfl_xor(v, 1, 16);
            v += __shfl_xor(v, 2, 16);
            v += __shfl_xor(v, 4, 16);
            v += __shfl_xor(v, 8, 16);
            acc[d][rr] = v;
        }

    // lane j == rr stores row lr+rr into LDS (zeroed if out-of-range)
#pragma unroll
    for (int rr = 0; rr < 4; ++rr) {
        if (j == rr) {
            const float vf = valid[rr] ? 1.0f : 0.0f;
#pragma unroll
            for (int d = 0; d < NJ; ++d) dlds[lr + rr][d] = acc[d][rr] * vf;
        }
    }

    __syncthreads();

    // epilogue: thread tid < TOUT handles output l = t*TOUT + tid
    if (tid < TOUT) {
        const int lo = t * TOUT + tid;
        if (lo < LL) {
            const int c = tid + 3;   // local dot-row of the center

            float pre3 = 0.0f, pre5 = 0.0f, pre7 = 0.0f;
#pragma unroll
            for (int tp = 0; tp < 3; ++tp) pre3 += dlds[c + tp - 1][tp];
#pragma unroll
            for (int tp = 0; tp < 5; ++tp) pre5 += dlds[c + tp - 2][4 + tp];
#pragma unroll
            for (int tp = 0; tp < 7; ++tp) pre7 += dlds[c + tp - 3][10 + tp];

            const float c3v = dlds[c][3];
            const float c5v = dlds[c][9];
            const float c7v = dlds[c][17];

            const float s3 = 1.0f / (1.0f + expf(-(pre3 + ab3[0])));
            const float s5 = 1.0f / (1.0f + expf(-(pre5 + ab5[0])));
            const float s7 = 1.0f / (1.0f + expf(-(pre7 + ab7[0])));

            const int r = b * LL + lo;
            out[r]             = tanhf(s3 * c3v + cb3[0]);
            out[NROWS + r]     = tanhf(s5 * c5v + cb5[0]);
            out[2 * NROWS + r] = tanhf(s7 * c7v + cb7[0]);
        }
    }
}

extern "C" void kernel_launch(void* const* d_in, const int* in_sizes, int n_in,
                              void* d_out, int out_size, void* d_ws, size_t ws_size,
                              hipStream_t stream) {
    const float* x   = (const float*)d_in[0];
    const float* aw3 = (const float*)d_in[1];
    const float* ab3 = (const float*)d_in[2];
    const float* cw3 = (const float*)d_in[3];
    const float* cb3 = (const float*)d_in[4];
    const float* aw5 = (const float*)d_in[5];
    const float* ab5 = (const float*)d_in[6];
    const float* cw5 = (const float*)d_in[7];
    const float* cb5 = (const float*)d_in[8];
    const float* aw7 = (const float*)d_in[9];
    const float* ab7 = (const float*)d_in[10];
    const float* cw7 = (const float*)d_in[11];
    const float* cb7 = (const float*)d_in[12];

    float* out = (float*)d_out;  // [out3 | out5 | out7]

    // 256 batches x 9 l-tiles, one dispatch, no workspace
    fused_kernel<<<BB * NTILE, 256, 0, stream>>>(
        x, aw3, ab3, cw3, cb3, aw5, ab5, cw5, cb5, aw7, ab7, cw7, cb7, out);
}

// Round 7
// 257.573 us; speedup vs baseline: 1.2884x; 1.0162x over previous
//
#include <hip/hip_runtime.h>
#include <math.h>

#define BB 256
#define LL 500
#define EE 300
#define NROWS (BB * LL)      // 128000
#define NJ 18                // 3 (aw3) + 1 (cw3) + 5 (aw5) + 1 (cw5) + 7 (aw7) + 1 (cw7)
#define NC 75                // float4 chunks per row
#define TOUT 56              // outputs per block
#define NTILE 9              // ceil(500/56)
#define DROWS 64             // dot rows per block = TOUT + 6 halo (+2 spare)

// ---------------------------------------------------------------------------
// Fully fused. R6 was latency-bound (VALUBusy 24%, ~80% idle): lockstep waves
// stalled together on the depth-1 x prefetch every chunk. Now ALL 20 x-float4
// per lane are loaded BEFORE the weight-staging barrier (the barrier's
// vmcnt(0) drain retires them); the main loop is pure VALU + LDS and cannot
// stall on global memory. Block = 256 thr = 4 waves; wave -> 4 groups x 16
// lanes; group -> 4 rows; 64 dot-rows/block -> 56 outputs. No workspace.
// ---------------------------------------------------------------------------
__global__ __launch_bounds__(256) void fused_kernel(
    const float* __restrict__ x,
    const float* __restrict__ aw3, const float* __restrict__ ab3,
    const float* __restrict__ cw3, const float* __restrict__ cb3,
    const float* __restrict__ aw5, const float* __restrict__ ab5,
    const float* __restrict__ cw5, const float* __restrict__ cb5,
    const float* __restrict__ aw7, const float* __restrict__ ab7,
    const float* __restrict__ cw7, const float* __restrict__ cb7,
    float* __restrict__ out)
{
    __shared__ float4 wlds[NJ * NC];         // 1350 float4 = 21.6 KB
    __shared__ float dlds[DROWS][NJ + 1];    // stride 19, conflict-free (4.9 KB)

    const int tid = threadIdx.x;

    // ---- cooperative weight staging: 6 contiguous segments ----
    // (issued first so the ds_writes' vmcnt deps are the OLDEST loads)
    {
        const float4* s3a = (const float4*)aw3;   // 225
        const float4* s3c = (const float4*)cw3;   // 75
        const float4* s5a = (const float4*)aw5;   // 375
        const float4* s5c = (const float4*)cw5;   // 75
        const float4* s7a = (const float4*)aw7;   // 525
        const float4* s7c = (const float4*)cw7;   // 75
        for (int i = tid; i < 225; i += 256) wlds[i]        = s3a[i];
        for (int i = tid; i < 75;  i += 256) wlds[225 + i]  = s3c[i];
        for (int i = tid; i < 375; i += 256) wlds[300 + i]  = s5a[i];
        for (int i = tid; i < 75;  i += 256) wlds[675 + i]  = s5c[i];
        for (int i = tid; i < 525; i += 256) wlds[750 + i]  = s7a[i];
        for (int i = tid; i < 75;  i += 256) wlds[1275 + i] = s7c[i];
    }

    const int b    = blockIdx.x / NTILE;
    const int t    = blockIdx.x % NTILE;
    const int l0   = t * TOUT - 3;           // global l of local dot-row 0
    const int wave = tid >> 6;               // 0..3
    const int lane = tid & 63;
    const int g    = lane >> 4;              // 0..3
    const int j    = lane & 15;              // 0..15
    const int lr   = wave * 16 + g * 4;      // local dot-row base (0..60)

    // clamped x row pointers + validity (invalid rows -> zero dots = zero pad)
    bool valid[4];
    const float4* xr[4];
#pragma unroll
    for (int rr = 0; rr < 4; ++rr) {
        const int l = l0 + lr + rr;
        valid[rr] = (l >= 0) && (l < LL);
        const int lc = l < 0 ? 0 : (l >= LL ? LL - 1 : l);
        xr[rr] = (const float4*)(x + ((size_t)b * LL + lc) * EE);
    }

    // ---- FULL x prefetch: all 5 chunks x 4 rows before the barrier ----
    // chunk k<4 -> column j+16k; k==4 -> j+64 (clamped dup for j>=11, unused)
    float4 xall[5][4];
#pragma unroll
    for (int k = 0; k < 5; ++k) {
        const int c = (k == 4) ? ((j < 11) ? (j + 64) : 74) : (j + 16 * k);
#pragma unroll
        for (int rr = 0; rr < 4; ++rr) xall[k][rr] = xr[rr][c];
    }

    __syncthreads();   // wlds visible; drains all x loads too (paid once)

    float acc[NJ][4];
#pragma unroll
    for (int d = 0; d < NJ; ++d)
#pragma unroll
        for (int rr = 0; rr < 4; ++rr) acc[d][rr] = 0.0f;

#define COMPUTE(k, c)                                                               \
    {                                                                               \
        _Pragma("unroll")                                                           \
        for (int d = 0; d < NJ; ++d) {                                              \
            const float4 w = wlds[d * NC + (c)];                                    \
            acc[d][0] = fmaf(xall[k][0].w, w.w, fmaf(xall[k][0].z, w.z, fmaf(xall[k][0].y, w.y, fmaf(xall[k][0].x, w.x, acc[d][0])))); \
            acc[d][1] = fmaf(xall[k][1].w, w.w, fmaf(xall[k][1].z, w.z, fmaf(xall[k][1].y, w.y, fmaf(xall[k][1].x, w.x, acc[d][1])))); \
            acc[d][2] = fmaf(xall[k][2].w, w.w, fmaf(xall[k][2].z, w.z, fmaf(xall[k][2].y, w.y, fmaf(xall[k][2].x, w.x, acc[d][2])))); \
            acc[d][3] = fmaf(xall[k][3].w, w.w, fmaf(xall[k][3].z, w.z, fmaf(xall[k][3].y, w.y, fmaf(xall[k][3].x, w.x, acc[d][3])))); \
        }                                                                           \
    }

    COMPUTE(0, j)
    COMPUTE(1, j + 16)
    COMPUTE(2, j + 32)
    COMPUTE(3, j + 48)
    if (j < 11) {
        COMPUTE(4, j + 64)
    }
#undef COMPUTE

    // butterfly reduce each (d, rr) across the 16-lane group
#pragma unroll
    for (int d = 0; d < NJ; ++d)
#pragma unroll
        for (int rr = 0; rr < 4; ++rr) {
            float v = acc[d][rr];
            v += __shfl_xor(v, 1, 16);
            v += __shfl_xor(v, 2, 16);
            v += __shfl_xor(v, 4, 16);
            v += __shfl_xor(v, 8, 16);
            acc[d][rr] = v;
        }

    // lane j == rr stores row lr+rr into LDS (zeroed if out-of-range)
#pragma unroll
    for (int rr = 0; rr < 4; ++rr) {
        if (j == rr) {
            const float vf = valid[rr] ? 1.0f : 0.0f;
#pragma unroll
            for (int d = 0; d < NJ; ++d) dlds[lr + rr][d] = acc[d][rr] * vf;
        }
    }

    __syncthreads();

    // epilogue: wave w (0..2) handles branch w, lanes 0..55 = output index.
    // wave-uniform branch selection, divergence-free across each wave.
    if (wave < 3 && lane < TOUT) {
        const int lo = t * TOUT + lane;
        if (lo < LL) {
            const int c = lane + 3;   // local dot-row of the center
            const int r = b * LL + lo;

            if (wave == 0) {
                float pre = 0.0f;
#pragma unroll
                for (int tp = 0; tp < 3; ++tp) pre += dlds[c + tp - 1][tp];
                const float s = 1.0f / (1.0f + expf(-(pre + ab3[0])));
                out[r] = tanhf(s * dlds[c][3] + cb3[0]);
            } else if (wave == 1) {
                float pre = 0.0f;
#pragma unroll
                for (int tp = 0; tp < 5; ++tp) pre += dlds[c + tp - 2][4 + tp];
                const float s = 1.0f / (1.0f + expf(-(pre + ab5[0])));
                out[NROWS + r] = tanhf(s * dlds[c][9] + cb5[0]);
            } else {
                float pre = 0.0f;
#pragma unroll
                for (int tp = 0; tp < 7; ++tp) pre += dlds[c + tp - 3][10 + tp];
                const float s = 1.0f / (1.0f + expf(-(pre + ab7[0])));
                out[2 * NROWS + r] = tanhf(s * dlds[c][17] + cb7[0]);
            }
        }
    }
}

extern "C" void kernel_launch(void* const* d_in, const int* in_sizes, int n_in,
                              void* d_out, int out_size, void* d_ws, size_t ws_size,
                              hipStream_t stream) {
    const float* x   = (const float*)d_in[0];
    const float* aw3 = (const float*)d_in[1];
    const float* ab3 = (const float*)d_in[2];
    const float* cw3 = (const float*)d_in[3];
    const float* cb3 = (const float*)d_in[4];
    const float* aw5 = (const float*)d_in[5];
    const float* ab5 = (const float*)d_in[6];
    const float* cw5 = (const float*)d_in[7];
    const float* cb5 = (const float*)d_in[8];
    const float* aw7 = (const float*)d_in[9];
    const float* ab7 = (const float*)d_in[10];
    const float* cw7 = (const float*)d_in[11];
    const float* cb7 = (const float*)d_in[12];

    float* out = (float*)d_out;  // [out3 | out5 | out7]

    // 256 batches x 9 l-tiles, one dispatch, no workspace
    fused_kernel<<<BB * NTILE, 256, 0, stream>>>(
        x, aw3, ab3, cw3, cb3, aw5, ab5, cw5, cb5, aw7, ab7, cw7, cb7, out);
}